// Round 6
// baseline (79.350 us; speedup 1.0000x reference)
//
#include <hip/hip_runtime.h>
#include <stdint.h>

typedef unsigned short u16;
typedef unsigned int u32;
typedef __bf16 bf16x8 __attribute__((ext_vector_type(8)));
typedef float f32x4 __attribute__((ext_vector_type(4)));

#define MFMA16 __builtin_amdgcn_mfma_f32_16x16x32_bf16

// ---------------- helpers ----------------

__device__ __forceinline__ u16 f2bf(float f) {
    u32 u = __builtin_bit_cast(u32, f);
    u32 r = (u + 0x7FFFu + ((u >> 16) & 1u)) >> 16;
    return (u16)r;
}

__device__ __forceinline__ void gload_lds16(const u16* g, u16* l) {
    __builtin_amdgcn_global_load_lds(
        (const __attribute__((address_space(1))) void*)g,
        (__attribute__((address_space(3))) void*)l,
        16, 0, 0);
}

// ================= kernel 1: merged conv_x + prep_w =================
// blocks [0, convBlocks): x fp32 -> bf16 (8 elems/thread).
// blocks [convBlocks, convBlocks+512): fused TT weight precompute ->
//   Wt[o*4+s][i] (bf16 [4096][1024]) = sum_{q,r} c0[b,w,q,s]*c1[q,c,x,r,s]*c2[r,d,y,s]
//   i=(b*128+c*8+d), o=(w*128+x*8+y); 512 blocks = (bc=128)x(part=4).

__global__ __launch_bounds__(256) void pre_kernel(const float* __restrict__ x,
                                                  const float* __restrict__ c0,
                                                  const float* __restrict__ c1,
                                                  const float* __restrict__ c2,
                                                  u16* __restrict__ xb,
                                                  u16* __restrict__ Wt,
                                                  int convBlocks, int nElem) {
    __shared__ float smem[10496];   // 41 KB: c0(256) c1(4096) c2(2048) w1(4096)
    const int t = threadIdx.x;

    if ((int)blockIdx.x < convBlocks) {
        int i = (blockIdx.x * 256 + t) * 8;
        if (i + 8 > nElem) return;
        float4 a = *reinterpret_cast<const float4*>(x + i);
        float4 b = *reinterpret_cast<const float4*>(x + i + 4);
        uint4 pk;
        pk.x = (u32)f2bf(a.x) | ((u32)f2bf(a.y) << 16);
        pk.y = (u32)f2bf(a.z) | ((u32)f2bf(a.w) << 16);
        pk.z = (u32)f2bf(b.x) | ((u32)f2bf(b.y) << 16);
        pk.w = (u32)f2bf(b.z) | ((u32)f2bf(b.w) << 16);
        *reinterpret_cast<uint4*>(xb + i) = pk;
        return;
    }

    float* l_c0 = smem;           // [w][q][s]     (slice at fixed b)
    float* l_c1 = smem + 256;     // [q][x][r][s]  (slice at fixed c)
    float* l_c2 = smem + 4352;    // [r][d][y][s]  (full)
    float* l_w1 = smem + 6400;    // [w][x][r][s]

    const int bid = blockIdx.x - convBlocks;
    const int bc = bid >> 2;      // 0..127
    const int part = bid & 3;     // 0..3 : w-pair {2p, 2p+1}
    const int b = bc >> 4, c = bc & 15;

    l_c0[t] = c0[b * 256 + t];
#pragma unroll
    for (int q = 0; q < 8; ++q) {
        l_c1[q * 512 + t]       = c1[(q * 16 + c) * 512 + t];
        l_c1[q * 512 + t + 256] = c1[(q * 16 + c) * 512 + t + 256];
    }
#pragma unroll
    for (int j = 0; j < 8; ++j) l_c2[t + 256 * j] = c2[t + 256 * j];
    __syncthreads();

    // W1[w][x][r][s] = sum_q c0[w,q,s] * c1[q,x,r,s]   (only w in {2p,2p+1})
#pragma unroll
    for (int j = 0; j < 4; ++j) {
        int idx = t + 256 * (part * 4 + j);   // ((w*16+x)*8+r)*4+s
        int s = idx & 3;
        int r = (idx >> 2) & 7;
        int xx = (idx >> 5) & 15;
        int w = idx >> 9;
        float acc = 0.f;
#pragma unroll
        for (int q = 0; q < 8; ++q)
            acc += l_c0[(w * 8 + q) * 4 + s] * l_c1[q * 512 + (xx * 8 + r) * 4 + s];
        l_w1[idx] = acc;
    }
    __syncthreads();

    // Wt[(o*4+s)][b*128+c*8+d] = sum_r W1[w,x,r,s] * c2[r,d,y,s]
#pragma unroll
    for (int j = 0; j < 4; ++j) {
        int idx = t + 256 * (part * 4 + j);   // ((w*16+x)*8+y)*4+s == o*4+s
        int s = idx & 3;
        int y = (idx >> 2) & 7;
        int xx = (idx >> 5) & 15;
        int w = idx >> 9;
        float acc[8] = {0.f, 0.f, 0.f, 0.f, 0.f, 0.f, 0.f, 0.f};
#pragma unroll
        for (int r = 0; r < 8; ++r) {
            float w1 = l_w1[((w * 16 + xx) * 8 + r) * 4 + s];
#pragma unroll
            for (int d = 0; d < 8; ++d)
                acc[d] += w1 * l_c2[((r * 8 + d) * 8 + y) * 4 + s];
        }
        uint4 pk;
        pk.x = (u32)f2bf(acc[0]) | ((u32)f2bf(acc[1]) << 16);
        pk.y = (u32)f2bf(acc[2]) | ((u32)f2bf(acc[3]) << 16);
        pk.z = (u32)f2bf(acc[4]) | ((u32)f2bf(acc[5]) << 16);
        pk.w = (u32)f2bf(acc[6]) | ((u32)f2bf(acc[7]) << 16);
        *reinterpret_cast<uint4*>(&Wt[(size_t)idx * 1024 + b * 128 + c * 8]) = pk;
    }
}

// ================= kernel 2: 256x256 fat-wave GEMM =================
// C[M][N] = A[M][K] * B[N][K]^T.  A = xb, B = Wt (both bf16 [4096][1024]).
// 256 threads = 4 waves (2M x 2N); per-wave output 128x128 = acc[8][8] 16x16
// frags (256 VGPR). FLOP per LDS byte = 64 (vs 43.7 for 8-wave 128x64).
// BK=32: one MFMA-K per step. 4 LDS slots per matrix (4 x 16 KB x 2 = 128 KiB),
// prefetch depth 2: stage slot kt+2 during step kt; ONE counted vmcnt(8) +
// ONE barrier per step (reader slot kt, writer slot kt+2 distinct mod 4 under
// <=1-step skew; previous contents of kt+2 slot retired 2 barriers ago).
//
// LDS swizzle (row stride 32 u16 = 64 B): bank = ((row&1)<<4)|(slot<<2)|dw.
// phys_slot = logical ^ ((row>>1)&3): 16 consecutive rows sweep all 8
// (row&1, slot) combos -> 2 lanes/bank -> free. Both-sides involution:
// linear global_load_lds dest + pre-swizzled global source column.
// NOTE: ((row>>1)&3) is invariant across a wave's f/g frag tiles (steps of 16
// rows), so the ds_read address is base + compile-time immediate offsets.

#define BK 32
#define SLOT_U16 8192   // 256 rows * 32 u16 = 16 KB

__global__ __launch_bounds__(256, 1) void gemm256_kernel(const u16* __restrict__ A,
                                                         const u16* __restrict__ B,
                                                         float* __restrict__ C,
                                                         int M, int N, int K) {
    __shared__ u16 As[4 * SLOT_U16];  // 64 KB
    __shared__ u16 Bs[4 * SLOT_U16];  // 64 KB

    const int t   = threadIdx.x;
    const int ln  = t & 63;
    const int wid = t >> 6;          // 0..3
    const int wr  = wid >> 1;        // 0..1 -> M offset wr*128
    const int wc  = wid & 1;         // 0..1 -> N offset wc*128
    const int m0  = blockIdx.y * 256;
    const int n0  = blockIdx.x * 256;
    const int NT  = K >> 5;          // 32 K-steps

    // fragment addressing (per-thread constant; frag index adds f*512 u16)
    const int frow  = ln & 15;
    const int ks    = ln >> 4;                       // logical k-slot 0..3
    const int arow0 = wr * 128 + frow;
    const int brow0 = wc * 128 + frow;
    const int aoff  = arow0 * 32 + (ks ^ ((arow0 >> 1) & 3)) * 8;
    const int boff  = brow0 * 32 + (ks ^ ((brow0 >> 1) & 3)) * 8;

    // staging: per matrix 1024 chunks of 16 B; thread t handles c = t + j*256.
    // row = c>>2; logical slot fetched = (c&3) ^ ((row>>1)&3); LDS dest linear.
    int srow[4], scol[4];
#pragma unroll
    for (int j = 0; j < 4; ++j) {
        int c = t + j * 256;
        srow[j] = c >> 2;
        scol[j] = ((c & 3) ^ ((srow[j] >> 1) & 3)) * 8;
    }

    f32x4 acc[8][8] = {};

#define STAGE(STEP)                                                          \
    {   const int kc_ = (STEP) * BK;                                         \
        u16* Ad_ = As + ((STEP) & 3) * SLOT_U16;                             \
        u16* Bd_ = Bs + ((STEP) & 3) * SLOT_U16;                             \
        _Pragma("unroll")                                                    \
        for (int j = 0; j < 4; ++j)                                          \
            gload_lds16(A + (size_t)(m0 + srow[j]) * K + kc_ + scol[j],      \
                        Ad_ + (t + j * 256) * 8);                            \
        _Pragma("unroll")                                                    \
        for (int j = 0; j < 4; ++j)                                          \
            gload_lds16(B + (size_t)(n0 + srow[j]) * K + kc_ + scol[j],      \
                        Bd_ + (t + j * 256) * 8);   }

    // ---- prologue: stage steps 0,1 ----
    STAGE(0);
    STAGE(1);
    asm volatile("s_waitcnt vmcnt(8)" ::: "memory");   // step 0 resident
    __builtin_amdgcn_sched_barrier(0);
    __builtin_amdgcn_s_barrier();
    __builtin_amdgcn_sched_barrier(0);

    for (int kt = 0; kt < NT; ++kt) {
        const u16* Ab = As + (kt & 3) * SLOT_U16 + aoff;
        const u16* Bb = Bs + (kt & 3) * SLOT_U16 + boff;

        if (kt + 2 < NT) STAGE(kt + 2);

        bf16x8 bfrag[8];
#pragma unroll
        for (int g = 0; g < 8; ++g)
            bfrag[g] = *reinterpret_cast<const bf16x8*>(Bb + g * 512);

#pragma unroll
        for (int f = 0; f < 8; ++f) {
            bf16x8 af = *reinterpret_cast<const bf16x8*>(Ab + f * 512);
#pragma unroll
            for (int g = 0; g < 8; ++g)
                acc[f][g] = MFMA16(af, bfrag[g], acc[f][g], 0, 0, 0);
        }

        // counted wait: kt+1's 8 loads must land; kt+2's 8 stay in flight.
        if (kt + 2 < NT) {
            asm volatile("s_waitcnt vmcnt(8)" ::: "memory");
        } else if (kt + 2 == NT) {
            asm volatile("s_waitcnt vmcnt(0)" ::: "memory");
        }
        __builtin_amdgcn_sched_barrier(0);
        __builtin_amdgcn_s_barrier();
        __builtin_amdgcn_sched_barrier(0);
    }
#undef STAGE

    // ---- epilogue: C/D layout col=lane&15, row=(lane>>4)*4+reg ----
    const int cr = (ln >> 4) * 4;
    const int cc = ln & 15;
#pragma unroll
    for (int f = 0; f < 8; ++f) {
#pragma unroll
        for (int r = 0; r < 4; ++r) {
            int row = m0 + wr * 128 + f * 16 + cr + r;
            float* p = C + (size_t)row * N + n0 + wc * 128 + cc;
#pragma unroll
            for (int g = 0; g < 8; ++g)
                p[g * 16] = acc[f][g][r];
        }
    }
}

// ---------------- launch ----------------

extern "C" void kernel_launch(void* const* d_in, const int* in_sizes, int n_in,
                              void* d_out, int out_size, void* d_ws, size_t ws_size,
                              hipStream_t stream) {
    const float* x  = (const float*)d_in[0];
    const float* c0 = (const float*)d_in[1];
    const float* c1 = (const float*)d_in[2];
    const float* c2 = (const float*)d_in[3];
    float* out = (float*)d_out;

    const int K = 1024;             // input dim
    const int N = 4096;             // OUT_DIM * SUP
    const int M = in_sizes[0] / K;  // tokens = B*S

    u16* xb = (u16*)d_ws;                        // M*K bf16
    u16* Wt = (u16*)d_ws + (size_t)M * K;        // N*K bf16

    const int convBlocks = (M * K) / (256 * 8);
    pre_kernel<<<convBlocks + 512, 256, 0, stream>>>(x, c0, c1, c2, xb, Wt,
                                                     convBlocks, M * K);

    dim3 g(N / 256, M / 256);
    gemm256_kernel<<<g, 256, 0, stream>>>(xb, Wt, out, M, N, K);
}

// Round 7
// 57.324 us; speedup vs baseline: 1.3842x; 1.3842x over previous
//
#include <hip/hip_runtime.h>
#include <stdint.h>

typedef unsigned short u16;
typedef unsigned int u32;
typedef __bf16 bf16x8 __attribute__((ext_vector_type(8)));
typedef float f32x4 __attribute__((ext_vector_type(4)));

#define MFMA16 __builtin_amdgcn_mfma_f32_16x16x32_bf16

// ---------------- helpers ----------------

__device__ __forceinline__ u16 f2bf(float f) {
    u32 u = __builtin_bit_cast(u32, f);
    u32 r = (u + 0x7FFFu + ((u >> 16) & 1u)) >> 16;
    return (u16)r;
}

__device__ __forceinline__ void gload_lds16(const u16* g, u16* l) {
    __builtin_amdgcn_global_load_lds(
        (const __attribute__((address_space(1))) void*)g,
        (__attribute__((address_space(3))) void*)l,
        16, 0, 0);
}

// ================= kernel 1: merged conv_x + prep_w =================
// blocks [0, convBlocks): x fp32 -> bf16 (8 elems/thread).
// blocks [convBlocks, convBlocks+512): fused TT weight precompute ->
//   Wt[o*4+s][i] (bf16 [4096][1024]) = sum_{q,r} c0[b,w,q,s]*c1[q,c,x,r,s]*c2[r,d,y,s]
//   i=(b*128+c*8+d), o=(w*128+x*8+y); 512 blocks = (bc=128)x(part=4).

__global__ __launch_bounds__(256) void pre_kernel(const float* __restrict__ x,
                                                  const float* __restrict__ c0,
                                                  const float* __restrict__ c1,
                                                  const float* __restrict__ c2,
                                                  u16* __restrict__ xb,
                                                  u16* __restrict__ Wt,
                                                  int convBlocks, int nElem) {
    __shared__ float smem[10496];   // 41 KB: c0(256) c1(4096) c2(2048) w1(4096)
    const int t = threadIdx.x;

    if ((int)blockIdx.x < convBlocks) {
        int i = (blockIdx.x * 256 + t) * 8;
        if (i + 8 > nElem) return;
        float4 a = *reinterpret_cast<const float4*>(x + i);
        float4 b = *reinterpret_cast<const float4*>(x + i + 4);
        uint4 pk;
        pk.x = (u32)f2bf(a.x) | ((u32)f2bf(a.y) << 16);
        pk.y = (u32)f2bf(a.z) | ((u32)f2bf(a.w) << 16);
        pk.z = (u32)f2bf(b.x) | ((u32)f2bf(b.y) << 16);
        pk.w = (u32)f2bf(b.z) | ((u32)f2bf(b.w) << 16);
        *reinterpret_cast<uint4*>(xb + i) = pk;
        return;
    }

    float* l_c0 = smem;           // [w][q][s]     (slice at fixed b)
    float* l_c1 = smem + 256;     // [q][x][r][s]  (slice at fixed c)
    float* l_c2 = smem + 4352;    // [r][d][y][s]  (full)
    float* l_w1 = smem + 6400;    // [w][x][r][s]

    const int bid = blockIdx.x - convBlocks;
    const int bc = bid >> 2;      // 0..127
    const int part = bid & 3;     // 0..3 : w-pair {2p, 2p+1}
    const int b = bc >> 4, c = bc & 15;

    l_c0[t] = c0[b * 256 + t];
#pragma unroll
    for (int q = 0; q < 8; ++q) {
        l_c1[q * 512 + t]       = c1[(q * 16 + c) * 512 + t];
        l_c1[q * 512 + t + 256] = c1[(q * 16 + c) * 512 + t + 256];
    }
#pragma unroll
    for (int j = 0; j < 8; ++j) l_c2[t + 256 * j] = c2[t + 256 * j];
    __syncthreads();

    // W1[w][x][r][s] = sum_q c0[w,q,s] * c1[q,x,r,s]   (only w in {2p,2p+1})
#pragma unroll
    for (int j = 0; j < 4; ++j) {
        int idx = t + 256 * (part * 4 + j);   // ((w*16+x)*8+r)*4+s
        int s = idx & 3;
        int r = (idx >> 2) & 7;
        int xx = (idx >> 5) & 15;
        int w = idx >> 9;
        float acc = 0.f;
#pragma unroll
        for (int q = 0; q < 8; ++q)
            acc += l_c0[(w * 8 + q) * 4 + s] * l_c1[q * 512 + (xx * 8 + r) * 4 + s];
        l_w1[idx] = acc;
    }
    __syncthreads();

    // Wt[(o*4+s)][b*128+c*8+d] = sum_r W1[w,x,r,s] * c2[r,d,y,s]
#pragma unroll
    for (int j = 0; j < 4; ++j) {
        int idx = t + 256 * (part * 4 + j);   // ((w*16+x)*8+y)*4+s == o*4+s
        int s = idx & 3;
        int y = (idx >> 2) & 7;
        int xx = (idx >> 5) & 15;
        int w = idx >> 9;
        float acc[8] = {0.f, 0.f, 0.f, 0.f, 0.f, 0.f, 0.f, 0.f};
#pragma unroll
        for (int r = 0; r < 8; ++r) {
            float w1 = l_w1[((w * 16 + xx) * 8 + r) * 4 + s];
#pragma unroll
            for (int d = 0; d < 8; ++d)
                acc[d] += w1 * l_c2[((r * 8 + d) * 8 + y) * 4 + s];
        }
        uint4 pk;
        pk.x = (u32)f2bf(acc[0]) | ((u32)f2bf(acc[1]) << 16);
        pk.y = (u32)f2bf(acc[2]) | ((u32)f2bf(acc[3]) << 16);
        pk.z = (u32)f2bf(acc[4]) | ((u32)f2bf(acc[5]) << 16);
        pk.w = (u32)f2bf(acc[6]) | ((u32)f2bf(acc[7]) << 16);
        *reinterpret_cast<uint4*>(&Wt[(size_t)idx * 1024 + b * 128 + c * 8]) = pk;
    }
}

// ================= kernel 2: 256x256 BK=64 4-phase GEMM =================
// C[M][N] = A[M][K] * B[N][K]^T.  A = xb, B = Wt (both bf16 [4096][1024]).
// 512 threads = 8 waves (2M x 4N); per-wave output 128x64 = acc[8][4].
// K-tile BK=64; 2 dbuf slots (128 KiB total). 4 phases/K-tile of 16 MFMA;
// B frags loaded once per K-tile and held in regs.
// SYNC DESIGN (this round's change): NO inline-asm waitcnts, NO sched_barrier.
// - intra-tile: raw s_barrier (scheduling rendezvous; data already resident,
//   compiler tracks ds_read->MFMA deps with fine-grained lgkmcnt).
// - tile boundary: __syncthreads() -- its implicit vmcnt(0) drain is exactly
//   the dbuf handoff (kt+1's 8 DMA loads, issued >=2 phases earlier).
// Every ds_read is consumed by MFMA before the wave's next barrier, so no
// read can still be in flight when the next tile's DMA writes land.
//
// LDS swizzle (row stride 128 B): 16-B chunk slot phys = logical ^ (row&7);
// both-sides involution (pre-swizzled global source + XOR'd ds_read).
//
// XCD swizzle (T1): 256 blocks -> 8 XCDs x (4 by x 8 bx) rectangles; per-XCD
// L2 panel traffic 16 MB -> 6 MB.

#define SLOT_U16 16384   // one dbuf slot of A (or B): 256 rows * 64 u16
#define HALF_U16 8192    // half-tile: 128 rows * 64 u16

#define BAR() __builtin_amdgcn_s_barrier()

__global__ __launch_bounds__(512, 2) void gemm256_kernel(const u16* __restrict__ A,
                                                         const u16* __restrict__ B,
                                                         float* __restrict__ C,
                                                         int M, int N, int K) {
    __shared__ u16 As[2 * SLOT_U16];  // 64 KB
    __shared__ u16 Bs[2 * SLOT_U16];  // 64 KB

    const int t   = threadIdx.x;
    const int ln  = t & 63;
    const int wid = t >> 6;          // 0..7
    const int wr  = wid >> 2;        // 0..1 -> M offset wr*128
    const int wc  = wid & 3;         // 0..3 -> N offset wc*64

    // ---- XCD-aware block swizzle: flat id -> (bx, by) rectangles ----
    const int bid = blockIdx.x;          // 0..255
    const int xcd = bid & 7;
    const int r   = bid >> 3;            // 0..31
    const int bx  = (xcd & 1) * 8 + (r & 7);
    const int by  = (xcd >> 1) * 4 + (r >> 3);
    const int m0  = by * 256;
    const int n0  = bx * 256;
    const int NT  = K >> 6;          // 16 K-tiles

    // fragment addressing: row = base + frow.
    const int frow  = ln & 15;
    const int ks    = ln >> 4;                       // logical k-slot 0..3
    const int arow  = wr * 128 + frow;
    const int brow  = wc * 64 + frow;
    const int koffa0 = ((ks ^ (arow & 7)) * 8);      // phys slot * 8 u16, k-half 0
    const int koffa1 = koffa0 ^ 32;                  // k-half 1 (slot ^ 4)
    const int koffb0 = ((ks ^ (brow & 7)) * 8);
    const int koffb1 = koffb0 ^ 32;

    // staging: half-tile = 1024 chunks of 16 B; thread t does chunks t, t+512.
    const int ca = t, cb = t + 512;
    const int pra = ca >> 3, lsa = (ca & 7) ^ ((ca >> 3) & 7);
    const int prb = cb >> 3, lsb = (cb & 7) ^ ((cb >> 3) & 7);

    f32x4 acc[8][4] = {};

    auto stage_half = [&](const u16* g /* global row0 of half at tile k-col */,
                          u16* l /* LDS half base */) {
        gload_lds16(g + (size_t)pra * K + lsa * 8, l + ca * 8);
        gload_lds16(g + (size_t)prb * K + lsb * 8, l + cb * 8);
    };

    // ---- prologue: stage all 4 halves of K-tile 0 into slot 0 ----
    stage_half(B + (size_t)n0 * K,          Bs);
    stage_half(B + (size_t)(n0 + 128) * K,  Bs + HALF_U16);
    stage_half(A + (size_t)m0 * K,          As);
    stage_half(A + (size_t)(m0 + 128) * K,  As + HALF_U16);
    __syncthreads();   // drains the DMA loads

    for (int kt = 0; kt < NT; ++kt) {
        const u16* Ab = As + (kt & 1) * SLOT_U16;
        const u16* Bb = Bs + (kt & 1) * SLOT_U16;
        u16* An = As + ((kt + 1) & 1) * SLOT_U16;
        u16* Bn = Bs + ((kt + 1) & 1) * SLOT_U16;
        const bool pf = (kt + 1) < NT;
        const int kc = (kt + 1) * 64;

        bf16x8 bf[4][2];
        bf16x8 a0k0, a0k1, a1k0, a1k1;

#define LOAD_A_PAIR(R0, R1)                                                  \
        {   const u16* ap0 = Ab + (size_t)(arow + (R0)) * 64;                \
            const u16* ap1 = Ab + (size_t)(arow + (R1)) * 64;                \
            a0k0 = *reinterpret_cast<const bf16x8*>(ap0 + koffa0);           \
            a0k1 = *reinterpret_cast<const bf16x8*>(ap0 + koffa1);           \
            a1k0 = *reinterpret_cast<const bf16x8*>(ap1 + koffa0);           \
            a1k1 = *reinterpret_cast<const bf16x8*>(ap1 + koffa1);  }

#define MFMA_PAIR(F0, F1)                                                    \
        _Pragma("unroll")                                                    \
        for (int n = 0; n < 4; ++n) {                                        \
            acc[F0][n] = MFMA16(a0k0, bf[n][0], acc[F0][n], 0, 0, 0);        \
            acc[F0][n] = MFMA16(a0k1, bf[n][1], acc[F0][n], 0, 0, 0);        \
            acc[F1][n] = MFMA16(a1k0, bf[n][0], acc[F1][n], 0, 0, 0);        \
            acc[F1][n] = MFMA16(a1k1, bf[n][1], acc[F1][n], 0, 0, 0);        \
        }

        // ======== phase 0: B frags + A f0,f1; stage next B ========
#pragma unroll
        for (int n = 0; n < 4; ++n) {
            const u16* bp = Bb + (size_t)(brow + n * 16) * 64;
            bf[n][0] = *reinterpret_cast<const bf16x8*>(bp + koffb0);
            bf[n][1] = *reinterpret_cast<const bf16x8*>(bp + koffb1);
        }
        LOAD_A_PAIR(0, 16);
        if (pf) {
            stage_half(B + (size_t)n0 * K + kc,         Bn);
            stage_half(B + (size_t)(n0 + 128) * K + kc, Bn + HALF_U16);
        }
        BAR();
        __builtin_amdgcn_s_setprio(1);
        MFMA_PAIR(0, 1);
        __builtin_amdgcn_s_setprio(0);
        BAR();

        // ======== phase 1: A f2,f3; stage next A ========
        LOAD_A_PAIR(32, 48);
        if (pf) {
            stage_half(A + (size_t)m0 * K + kc,         An);
            stage_half(A + (size_t)(m0 + 128) * K + kc, An + HALF_U16);
        }
        BAR();
        __builtin_amdgcn_s_setprio(1);
        MFMA_PAIR(2, 3);
        __builtin_amdgcn_s_setprio(0);
        BAR();

        // ======== phase 2: A f4,f5 ========
        LOAD_A_PAIR(64, 80);
        BAR();
        __builtin_amdgcn_s_setprio(1);
        MFMA_PAIR(4, 5);
        __builtin_amdgcn_s_setprio(0);
        BAR();

        // ======== phase 3: A f6,f7; tile-boundary handoff ========
        LOAD_A_PAIR(96, 112);
        BAR();
        __builtin_amdgcn_s_setprio(1);
        MFMA_PAIR(6, 7);
        __builtin_amdgcn_s_setprio(0);
        __syncthreads();   // implicit vmcnt(0): kt+1's DMA resident; dbuf flip

#undef LOAD_A_PAIR
#undef MFMA_PAIR
    }

    // ---- epilogue: C/D layout col=lane&15, row=(lane>>4)*4+reg ----
    const int cr = (ln >> 4) * 4;
    const int cc = ln & 15;
#pragma unroll
    for (int fm = 0; fm < 8; ++fm) {
#pragma unroll
        for (int rr = 0; rr < 4; ++rr) {
            int row = m0 + wr * 128 + fm * 16 + cr + rr;
            float* p = C + (size_t)row * N + n0 + wc * 64 + cc;
#pragma unroll
            for (int fn = 0; fn < 4; ++fn)
                p[fn * 16] = acc[fm][fn][rr];
        }
    }
}

// ---------------- launch ----------------

extern "C" void kernel_launch(void* const* d_in, const int* in_sizes, int n_in,
                              void* d_out, int out_size, void* d_ws, size_t ws_size,
                              hipStream_t stream) {
    const float* x  = (const float*)d_in[0];
    const float* c0 = (const float*)d_in[1];
    const float* c1 = (const float*)d_in[2];
    const float* c2 = (const float*)d_in[3];
    float* out = (float*)d_out;

    const int K = 1024;             // input dim
    const int N = 4096;             // OUT_DIM * SUP
    const int M = in_sizes[0] / K;  // tokens = B*S

    u16* xb = (u16*)d_ws;                        // M*K bf16
    u16* Wt = (u16*)d_ws + (size_t)M * K;        // N*K bf16

    const int convBlocks = (M * K) / (256 * 8);
    pre_kernel<<<convBlocks + 512, 256, 0, stream>>>(x, c0, c1, c2, xb, Wt,
                                                     convBlocks, M * K);

    gemm256_kernel<<<(N / 256) * (M / 256), 512, 0, stream>>>(xb, Wt, out, M, N, K);
}